// Round 4
// baseline (847.421 us; speedup 1.0000x reference)
//
#include <hip/hip_runtime.h>
#include <stdint.h>

typedef unsigned short u16;
typedef float f32x4 __attribute__((ext_vector_type(4)));
typedef __bf16 v8bf __attribute__((ext_vector_type(8)));

static __device__ __forceinline__ float bf2f(u16 u) {
  union { uint32_t i; float f; } v; v.i = ((uint32_t)u) << 16; return v.f;
}
static __device__ __forceinline__ u16 f2bf(float f) {
  union { float f; uint32_t i; } v; v.f = f;
  uint32_t b = v.i;
  return (u16)((b + 0x7FFFu + ((b >> 16) & 1u)) >> 16);
}

// ---------------- K1: LayerNorm over C=96 (fp32 in) -> bf16 xn ----------------
__global__ __launch_bounds__(256) void k_ln(const float* __restrict__ x,
                                            const float* __restrict__ gamma,
                                            const float* __restrict__ beta,
                                            u16* __restrict__ xn) {
  int tid = threadIdx.x;
  int vox = blockIdx.x * 64 + (tid >> 2);
  int q = tid & 3;
  const float4* px = (const float4*)(x + (size_t)vox * 96 + q * 24);
  float f[24];
  *(float4*)&f[0]  = px[0]; *(float4*)&f[4]  = px[1]; *(float4*)&f[8]  = px[2];
  *(float4*)&f[12] = px[3]; *(float4*)&f[16] = px[4]; *(float4*)&f[20] = px[5];
  float s = 0.f, s2 = 0.f;
#pragma unroll
  for (int i = 0; i < 24; ++i) { s += f[i]; s2 += f[i] * f[i]; }
  s += __shfl_xor(s, 1);  s += __shfl_xor(s, 2);
  s2 += __shfl_xor(s2, 1); s2 += __shfl_xor(s2, 2);
  float mu = s * (1.f / 96.f);
  float var = s2 * (1.f / 96.f) - mu * mu;
  float rs = rsqrtf(var + 1e-5f);
  uint32_t ow[12];
#pragma unroll
  for (int i = 0; i < 12; ++i) {
    int c0 = q * 24 + 2 * i;
    float v0 = (f[2 * i]     - mu) * rs * gamma[c0]     + beta[c0];
    float v1 = (f[2 * i + 1] - mu) * rs * gamma[c0 + 1] + beta[c0 + 1];
    ow[i] = (uint32_t)f2bf(v0) | ((uint32_t)f2bf(v1) << 16);
  }
  uint4* po = (uint4*)(xn + (size_t)vox * 96 + q * 24);
  po[0] = *(uint4*)&ow[0]; po[1] = *(uint4*)&ow[4]; po[2] = *(uint4*)&ow[8];
}

// ---------------- K2: repack qkv_w (fp32) into bf16 MFMA B-fragment layout ----------------
// Wb[tap][ks][nt][lane][j] : value = W[tap][ci=ks*32+(lane>>4)*8+j][co=nt*16+(lane&15)]
__global__ __launch_bounds__(256) void k_repack(const float* __restrict__ qw,
                                                u16* __restrict__ Wb) {
  int t = blockIdx.x * 256 + threadIdx.x;
  if (t >= 27 * 3 * 18 * 64) return;
  int l = t & 63;
  int rest = t >> 6;
  int nt = rest % 18;
  int ks = (rest / 18) % 3;
  int tap = rest / 54;
  int co = nt * 16 + (l & 15);
  int cibase = ks * 32 + (l >> 4) * 8;
  u16 vals[8];
#pragma unroll
  for (int j = 0; j < 8; ++j)
    vals[j] = f2bf(qw[((size_t)tap * 96 + cibase + j) * 288 + co]);
  *(uint4*)(Wb + (size_t)t * 8) = *(uint4*)vals;
}

// ---------------- K0: zero scratch floats ----------------
__global__ __launch_bounds__(256) void k_zero(float* p, int n) {
  int i = blockIdx.x * 256 + threadIdx.x;
  if (i < n) p[i] = 0.f;
}

// ---------------- K3: conv3d 3x3x3 96->288 via MFMA bf16 ----------------
// Block = TWO adjacent (x0,y0/y0+1) z-columns (128 output rows), 4 waves.
// Wave w: column (w>>1), N-half (w&1); M=64 per wave (4 A-frags) so each
// B fragment feeds 4 MFMAs -> B VMEM per CU halves vs 1-col blocks.
// A staged in LDS per (dx,dy) with z-halo; B read directly from global (L2-hot).
__global__ __launch_bounds__(256, 2) void k_conv(const u16* __restrict__ xn,
                                                 const u16* __restrict__ Wb,
                                                 const float* __restrict__ qkvb,
                                                 u16* __restrict__ y) {
  __shared__ u16 As[2 * 66 * 104];  // 27,456 B; pitch 104 u16 (2-way benign)
  int tid = threadIdx.x;
  // bijective XCD swizzle: 2048 blocks, 8 XCDs, 256 blocks/XCD.
  int bid = blockIdx.x;
  int swz = (bid & 7) * 256 + (bid >> 3);
  int x0 = swz >> 5;
  int y0 = (swz & 31) * 2;
  int lane = tid & 63, w = tid >> 6;
  int col = w >> 1, wc = w & 1;

  f32x4 acc[4][9];
#pragma unroll
  for (int m = 0; m < 4; ++m)
#pragma unroll
    for (int n = 0; n < 9; ++n) acc[m][n] = (f32x4)0.f;

  // wave-uniform base into Wb for this wave's N-half; per-lane 16B fragment
  const u16* wbase = Wb + (size_t)(wc * 9) * 512 + (size_t)lane * 8;

  for (int dxy = 0; dxy < 9; ++dxy) {
    int dx = dxy / 3, dy = dxy % 3;
    int xx = x0 + dx - 1;
    __syncthreads();
    for (int i = tid; i < 2 * 66 * 12; i += 256) {
      int c = i / 792, rem = i - c * 792;
      int row = rem / 12, c8 = rem - row * 12;
      int yy = y0 + c + dy - 1;
      uint4 v = make_uint4(0u, 0u, 0u, 0u);
      if (((unsigned)xx < 64u) && ((unsigned)yy < 64u) && row >= 1 && row <= 64) {
        const uint4* src = (const uint4*)(xn + ((size_t)(xx * 64 + yy) * 64) * 96);
        v = src[(row - 1) * 12 + c8];
      }
      *(uint4*)&As[(c * 66 + row) * 104 + c8 * 8] = v;
    }
    __syncthreads();

#pragma unroll
    for (int dz = 0; dz < 3; ++dz) {
      int tap = dxy * 3 + dz;
#pragma unroll
      for (int ks = 0; ks < 3; ++ks) {
        int ar = (lane & 15) + dz;
        int ac = ks * 32 + (lane >> 4) * 8;
        const u16* abase = &As[(col * 66 + ar) * 104 + ac];
        v8bf a0 = *(const v8bf*)(abase);
        v8bf a1 = *(const v8bf*)(abase + 16 * 104);
        v8bf a2 = *(const v8bf*)(abase + 32 * 104);
        v8bf a3 = *(const v8bf*)(abase + 48 * 104);
        const u16* bptr = wbase + (size_t)(tap * 3 + ks) * 9216;
#pragma unroll
        for (int nt = 0; nt < 9; ++nt) {
          v8bf b = *(const v8bf*)(bptr + (size_t)nt * 512);
          acc[0][nt] = __builtin_amdgcn_mfma_f32_16x16x32_bf16(a0, b, acc[0][nt], 0, 0, 0);
          acc[1][nt] = __builtin_amdgcn_mfma_f32_16x16x32_bf16(a1, b, acc[1][nt], 0, 0, 0);
          acc[2][nt] = __builtin_amdgcn_mfma_f32_16x16x32_bf16(a2, b, acc[2][nt], 0, 0, 0);
          acc[3][nt] = __builtin_amdgcn_mfma_f32_16x16x32_bf16(a3, b, acc[3][nt], 0, 0, 0);
        }
      }
    }
  }

  size_t voxbase = ((size_t)x0 * 64 + (y0 + col)) * 64;
#pragma unroll
  for (int m = 0; m < 4; ++m)
#pragma unroll
    for (int nt = 0; nt < 9; ++nt) {
      int colo = wc * 144 + nt * 16 + (lane & 15);
      float bias = qkvb[colo];
#pragma unroll
      for (int r = 0; r < 4; ++r) {
        int vrow = m * 16 + (lane >> 4) * 4 + r;
        y[(voxbase + vrow) * 288 + colo] = f2bf(acc[m][nt][r] + bias);
      }
    }
}

// ---------------- K4: Gram S[f,h,c,d] = sum_g q.k, plus norms ----------------
__global__ __launch_bounds__(256) void k_gram(const u16* __restrict__ y,
                                              float* __restrict__ S,
                                              float* __restrict__ qn2,
                                              float* __restrict__ kn2) {
  __shared__ u16 qk[8 * 192];
  int tid = threadIdx.x;
  int f = blockIdx.x >> 4, chunk = blockIdx.x & 15;
  int fx = f >> 4, fy = (f >> 2) & 3, fz = f & 3;
  int h = tid >> 6;
  int e0 = tid * 9;
  int ci[9], di[9];
#pragma unroll
  for (int i = 0; i < 9; ++i) {
    int rem = (e0 + i) % 576;
    ci[i] = rem / 24; di[i] = rem % 24;
  }
  float cacc[9];
#pragma unroll
  for (int i = 0; i < 9; ++i) cacc[i] = 0.f;
  float nacc = 0.f;

  for (int grp = 0; grp < 32; ++grp) {
    __syncthreads();
    for (int i = tid; i < 192; i += 256) {
      int rr = i / 24, c8 = i - rr * 24;
      int g = chunk * 256 + grp * 8 + rr;
      int gx = g >> 8, gy = (g >> 4) & 15, gz = g & 15;
      size_t vox = ((size_t)(gx * 4 + fx) * 64 + (gy * 4 + fy)) * 64 + (gz * 4 + fz);
      *(uint4*)&qk[rr * 192 + c8 * 8] = *(const uint4*)(y + vox * 288 + c8 * 8);
    }
    __syncthreads();
#pragma unroll 2
    for (int r = 0; r < 8; ++r) {
      const u16* row = &qk[r * 192];
#pragma unroll
      for (int i = 0; i < 9; ++i) {
        float qv = bf2f(row[h * 24 + ci[i]]);
        float kv = bf2f(row[96 + h * 24 + di[i]]);
        cacc[i] += qv * kv;
      }
      if (tid < 192) { float v = bf2f(row[tid]); nacc += v * v; }
    }
  }
  float* Sf = S + (size_t)f * 2304;
#pragma unroll
  for (int i = 0; i < 9; ++i) atomicAdd(&Sf[e0 + i], cacc[i]);
  if (tid < 96) atomicAdd(&qn2[f * 96 + tid], nacc);
  else if (tid < 192) atomicAdd(&kn2[f * 96 + tid - 96], nacc);
}

// ---------------- K5: normalize + softmax + fold out_w -> Mt[f][j][c'] (bf16) ----------------
__global__ __launch_bounds__(256) void k_attn(const float* __restrict__ S,
                                              const float* __restrict__ qn2,
                                              const float* __restrict__ kn2,
                                              const float* __restrict__ out_w,
                                              const float* __restrict__ temp,
                                              u16* __restrict__ Mt) {
  __shared__ float attn[2304];
  __shared__ float invq[96], invk[96];
  __shared__ float ow[9216];
  int tid = threadIdx.x;
  int f = blockIdx.x;
  if (tid < 96) {
    invq[tid] = 1.f / fmaxf(sqrtf(qn2[f * 96 + tid]), 1e-12f);
    invk[tid] = 1.f / fmaxf(sqrtf(kn2[f * 96 + tid]), 1e-12f);
  }
  for (int i = tid; i < 9216; i += 256) ow[i] = out_w[i];
  __syncthreads();
  if (tid < 96) {
    int h = tid / 24, c = tid % 24;
    float tmp = temp[h];
    const float* Sr = S + (size_t)f * 2304 + (size_t)h * 576 + c * 24;
    float lg[24];
    float mx = -1e30f;
#pragma unroll
    for (int d = 0; d < 24; ++d) {
      lg[d] = Sr[d] * invq[tid] * invk[h * 24 + d] * tmp;
      mx = fmaxf(mx, lg[d]);
    }
    float sum = 0.f;
#pragma unroll
    for (int d = 0; d < 24; ++d) { lg[d] = __expf(lg[d] - mx); sum += lg[d]; }
    float inv = 1.f / sum;
#pragma unroll
    for (int d = 0; d < 24; ++d) attn[h * 576 + c * 24 + d] = lg[d] * inv;
  }
  __syncthreads();
  for (int o = tid; o < 9216; o += 256) {
    int j = o / 96, cp = o - j * 96;
    int h2 = j / 24, d = j % 24;
    float s = 0.f;
#pragma unroll
    for (int cc = 0; cc < 24; ++cc)
      s += attn[h2 * 576 + cc * 24 + d] * ow[cp * 96 + h2 * 24 + cc];
    Mt[(size_t)f * 9216 + o] = f2bf(s);
  }
}

// ---------------- K6: out = Mt[f] @ v + out_b + x (residual), fp32 out ----------------
__global__ __launch_bounds__(256, 1) void k_final(const u16* __restrict__ y,
                                                  const u16* __restrict__ Mt,
                                                  const float* __restrict__ xin,
                                                  const float* __restrict__ out_b,
                                                  float* __restrict__ out) {
  __shared__ u16 mt4[4 * 9216];  // 73728 B: Mt for fz=0..3
  __shared__ u16 vst[64 * 96];   // 12288 B: one column's v
  int tid = threadIdx.x;
  int b = blockIdx.x;
  int fxy = b >> 4, chunk = b & 15;
  int fx = fxy >> 2, fy = fxy & 3;
  int x = fx + 4 * chunk;
  const uint4* msrc = (const uint4*)(Mt + (size_t)(fx * 16 + fy * 4) * 9216);
  for (int i = tid; i < 4608; i += 256) ((uint4*)mt4)[i] = msrc[i];
  int vox = tid >> 2, qo = tid & 3, fz = vox & 3;
  float ob[24];
#pragma unroll
  for (int cc = 0; cc < 24; ++cc) ob[cc] = out_b[qo * 24 + cc];

  for (int m = 0; m < 16; ++m) {
    int yy = fy + 4 * m;
    size_t colvox = ((size_t)x * 64 + yy) * 64;
    __syncthreads();
    for (int i = tid; i < 768; i += 256) {
      int vv = i / 12, c8 = i - vv * 12;
      ((uint4*)vst)[vv * 12 + c8] =
          *(const uint4*)(y + (colvox + vv) * 288 + 192 + c8 * 8);
    }
    __syncthreads();
    float acc[24];
#pragma unroll
    for (int cc = 0; cc < 24; ++cc) acc[cc] = ob[cc];
    const u16* mslice = &mt4[fz * 9216 + qo * 24];
#pragma unroll 4
    for (int j = 0; j < 96; ++j) {
      float vj = bf2f(vst[vox * 96 + j]);
      const uint4* mq = (const uint4*)(mslice + j * 96);
      uint4 m0 = mq[0], m1 = mq[1], m2 = mq[2];
      uint32_t mw[12];
      *(uint4*)&mw[0] = m0; *(uint4*)&mw[4] = m1; *(uint4*)&mw[8] = m2;
#pragma unroll
      for (int i2 = 0; i2 < 12; ++i2) {
        union { uint32_t u; float f; } lo, hi;
        lo.u = mw[i2] << 16; hi.u = mw[i2] & 0xFFFF0000u;
        acc[2 * i2] += vj * lo.f;
        acc[2 * i2 + 1] += vj * hi.f;
      }
    }
    const float4* xs = (const float4*)(xin + (colvox + vox) * 96 + qo * 24);
    float4* op = (float4*)(out + (colvox + vox) * 96 + qo * 24);
#pragma unroll
    for (int i2 = 0; i2 < 6; ++i2) {
      float4 xv = xs[i2];
      float4 r;
      r.x = acc[4 * i2 + 0] + xv.x;
      r.y = acc[4 * i2 + 1] + xv.y;
      r.z = acc[4 * i2 + 2] + xv.z;
      r.w = acc[4 * i2 + 3] + xv.w;
      op[i2] = r;
    }
  }
}

extern "C" void kernel_launch(void* const* d_in, const int* in_sizes, int n_in,
                              void* d_out, int out_size, void* d_ws, size_t ws_size,
                              hipStream_t stream) {
  const float* x  = (const float*)d_in[0];
  const float* g  = (const float*)d_in[1];
  const float* be = (const float*)d_in[2];
  const float* qw = (const float*)d_in[3];
  const float* qb = (const float*)d_in[4];
  const float* ow = (const float*)d_in[5];
  const float* ob = (const float*)d_in[6];
  const float* tp = (const float*)d_in[7];
  float* out = (float*)d_out;

  // xn (bf16, 50.3 MB) lives in d_out scratch space; dead before k_final
  // overwrites d_out with the final fp32 result.
  u16* xn = (u16*)d_out;

  char* w = (char*)d_ws;
  u16* y    = (u16*)(w);                          // 150,994,944 B
  u16* Wb   = (u16*)(w + 150994944);              // 1,492,992 B
  float* S  = (float*)(w + 152487936);            // 589,824 B
  float* qn2 = (float*)(w + 153077760);           // 24,576 B
  float* kn2 = (float*)(w + 153102336);           // 24,576 B
  u16* Mt   = (u16*)(w + 153126912);              // 1,179,648 B (end ~154.3 MB)

  hipLaunchKernelGGL(k_ln, dim3(4096), dim3(256), 0, stream, x, g, be, xn);
  hipLaunchKernelGGL(k_repack, dim3((27 * 3 * 18 * 64 + 255) / 256), dim3(256), 0, stream, qw, Wb);
  hipLaunchKernelGGL(k_zero, dim3(624), dim3(256), 0, stream, S, 159744);
  hipLaunchKernelGGL(k_conv, dim3(2048), dim3(256), 0, stream, xn, Wb, qb, y);
  hipLaunchKernelGGL(k_gram, dim3(1024), dim3(256), 0, stream, y, S, qn2, kn2);
  hipLaunchKernelGGL(k_attn, dim3(64), dim3(256), 0, stream, S, qn2, kn2, ow, tp, Mt);
  hipLaunchKernelGGL(k_final, dim3(256), dim3(256), 0, stream, y, Mt, x, ob, out);
}

// Round 5
// 757.599 us; speedup vs baseline: 1.1186x; 1.1186x over previous
//
#include <hip/hip_runtime.h>
#include <stdint.h>

typedef unsigned short u16;
typedef float f32x4 __attribute__((ext_vector_type(4)));
typedef __bf16 v8bf __attribute__((ext_vector_type(8)));

static __device__ __forceinline__ float bf2f(u16 u) {
  union { uint32_t i; float f; } v; v.i = ((uint32_t)u) << 16; return v.f;
}
static __device__ __forceinline__ u16 f2bf(float f) {
  union { float f; uint32_t i; } v; v.f = f;
  uint32_t b = v.i;
  return (u16)((b + 0x7FFFu + ((b >> 16) & 1u)) >> 16);
}

// ---------------- K1: LayerNorm over C=96 (fp32 in) -> bf16 xn ----------------
__global__ __launch_bounds__(256) void k_ln(const float* __restrict__ x,
                                            const float* __restrict__ gamma,
                                            const float* __restrict__ beta,
                                            u16* __restrict__ xn) {
  int tid = threadIdx.x;
  int vox = blockIdx.x * 64 + (tid >> 2);
  int q = tid & 3;
  const float4* px = (const float4*)(x + (size_t)vox * 96 + q * 24);
  float f[24];
  *(float4*)&f[0]  = px[0]; *(float4*)&f[4]  = px[1]; *(float4*)&f[8]  = px[2];
  *(float4*)&f[12] = px[3]; *(float4*)&f[16] = px[4]; *(float4*)&f[20] = px[5];
  float s = 0.f, s2 = 0.f;
#pragma unroll
  for (int i = 0; i < 24; ++i) { s += f[i]; s2 += f[i] * f[i]; }
  s += __shfl_xor(s, 1);  s += __shfl_xor(s, 2);
  s2 += __shfl_xor(s2, 1); s2 += __shfl_xor(s2, 2);
  float mu = s * (1.f / 96.f);
  float var = s2 * (1.f / 96.f) - mu * mu;
  float rs = rsqrtf(var + 1e-5f);
  uint32_t ow[12];
#pragma unroll
  for (int i = 0; i < 12; ++i) {
    int c0 = q * 24 + 2 * i;
    float v0 = (f[2 * i]     - mu) * rs * gamma[c0]     + beta[c0];
    float v1 = (f[2 * i + 1] - mu) * rs * gamma[c0 + 1] + beta[c0 + 1];
    ow[i] = (uint32_t)f2bf(v0) | ((uint32_t)f2bf(v1) << 16);
  }
  uint4* po = (uint4*)(xn + (size_t)vox * 96 + q * 24);
  po[0] = *(uint4*)&ow[0]; po[1] = *(uint4*)&ow[4]; po[2] = *(uint4*)&ow[8];
}

// ---------------- K2: repack qkv_w (fp32) into bf16 MFMA B-fragment layout ----------------
// Wb[tap][ks][nt][lane][j] : value = W[tap][ci=ks*32+(lane>>4)*8+j][co=nt*16+(lane&15)]
__global__ __launch_bounds__(256) void k_repack(const float* __restrict__ qw,
                                                u16* __restrict__ Wb) {
  int t = blockIdx.x * 256 + threadIdx.x;
  if (t >= 27 * 3 * 18 * 64) return;
  int l = t & 63;
  int rest = t >> 6;
  int nt = rest % 18;
  int ks = (rest / 18) % 3;
  int tap = rest / 54;
  int co = nt * 16 + (l & 15);
  int cibase = ks * 32 + (l >> 4) * 8;
  u16 vals[8];
#pragma unroll
  for (int j = 0; j < 8; ++j)
    vals[j] = f2bf(qw[((size_t)tap * 96 + cibase + j) * 288 + co]);
  *(uint4*)(Wb + (size_t)t * 8) = *(uint4*)vals;
}

// ---------------- K0: zero scratch floats ----------------
__global__ __launch_bounds__(256) void k_zero(float* p, int n) {
  int i = blockIdx.x * 256 + threadIdx.x;
  if (i < n) p[i] = 0.f;
}

// ---------------- K3: conv3d 3x3x3 96->288 via MFMA bf16 ----------------
// Block = TWO adjacent z-columns (128 rows), 4 waves; wave = 1 column x 144 cols.
// A: double-buffered LDS (stage dxy+1 after compute of dxy; 1 barrier/dxy).
// B: register-rotated 1-deep pipeline: b[nt] for the NEXT (tap,ks) is loaded
// right after the 4 MFMAs consuming the current one -> each load gets a
// ~36-MFMA window to cover L2 latency. Wb is contiguous in (dxy,dz,ks) so the
// rotation runs across dxy boundaries without special-casing.
__global__ __launch_bounds__(256, 2) void k_conv(const u16* __restrict__ xn,
                                                 const u16* __restrict__ Wb,
                                                 const float* __restrict__ qkvb,
                                                 u16* __restrict__ y) {
  __shared__ u16 As[2][2 * 66 * 104];  // 54,912 B total; pitch 104 (2-way benign)
  int tid = threadIdx.x;
  // bijective XCD swizzle: 2048 blocks, 8 XCDs, 256 blocks/XCD.
  int bid = blockIdx.x;
  int swz = (bid & 7) * 256 + (bid >> 3);
  int x0 = swz >> 5;
  int y0 = (swz & 31) * 2;
  int lane = tid & 63, w = tid >> 6;
  int wcol = w >> 1, wc = w & 1;

  f32x4 acc[4][9];
#pragma unroll
  for (int m = 0; m < 4; ++m)
#pragma unroll
    for (int n = 0; n < 9; ++n) acc[m][n] = (f32x4)0.f;

  // wave-uniform base into Wb for this wave's N-half; per-lane 16B fragment
  const u16* wbase = Wb + (size_t)(wc * 9) * 512 + (size_t)lane * 8;

  // ---- stage helper (expanded inline twice) ----
#define STAGE_A(DXY, BUF)                                                      \
  {                                                                            \
    int dx_ = (DXY) / 3, dy_ = (DXY) % 3;                                      \
    int xx_ = x0 + dx_ - 1;                                                    \
    for (int i = tid; i < 2 * 66 * 12; i += 256) {                             \
      int c_ = i / 792, rem_ = i - c_ * 792;                                   \
      int row_ = rem_ / 12, c8_ = rem_ - row_ * 12;                            \
      int yy_ = y0 + c_ + dy_ - 1;                                             \
      uint4 v_ = make_uint4(0u, 0u, 0u, 0u);                                   \
      if (((unsigned)xx_ < 64u) && ((unsigned)yy_ < 64u) && row_ >= 1 &&       \
          row_ <= 64) {                                                        \
        const uint4* src_ = (const uint4*)(xn + ((size_t)(xx_ * 64 + yy_) * 64) * 96); \
        v_ = src_[(row_ - 1) * 12 + c8_];                                      \
      }                                                                        \
      *(uint4*)&As[BUF][(c_ * 66 + row_) * 104 + c8_ * 8] = v_;                \
    }                                                                          \
  }

  STAGE_A(0, 0);
  __syncthreads();

  // preload B for (dxy=0, t=0)
  v8bf b[9];
#pragma unroll
  for (int nt = 0; nt < 9; ++nt)
    b[nt] = *(const v8bf*)(wbase + (size_t)nt * 512);

  for (int dxy = 0; dxy < 9; ++dxy) {
    const u16* Ab = &As[dxy & 1][0];
    const u16* base2 = wbase + (size_t)dxy * 9 * 9216;
    bool last_dxy = (dxy == 8);

#pragma unroll
    for (int t = 0; t < 9; ++t) {
      int dz = t / 3, ks = t - dz * 3;
      int ar = (lane & 15) + dz;
      int ac = ks * 32 + (lane >> 4) * 8;
      const u16* abase = &Ab[(wcol * 66 + ar) * 104 + ac];
      v8bf a0 = *(const v8bf*)(abase);
      v8bf a1 = *(const v8bf*)(abase + 16 * 104);
      v8bf a2 = *(const v8bf*)(abase + 32 * 104);
      v8bf a3 = *(const v8bf*)(abase + 48 * 104);
      // next (tap,ks) B base: contiguous across dxy boundary
      const u16* bnxt = base2 + (size_t)(t + 1) * 9216;
      bool more = (t < 8) || !last_dxy;
      __builtin_amdgcn_s_setprio(1);
#pragma unroll
      for (int nt = 0; nt < 9; ++nt) {
        v8bf bb = b[nt];
        acc[0][nt] = __builtin_amdgcn_mfma_f32_16x16x32_bf16(a0, bb, acc[0][nt], 0, 0, 0);
        acc[1][nt] = __builtin_amdgcn_mfma_f32_16x16x32_bf16(a1, bb, acc[1][nt], 0, 0, 0);
        acc[2][nt] = __builtin_amdgcn_mfma_f32_16x16x32_bf16(a2, bb, acc[2][nt], 0, 0, 0);
        acc[3][nt] = __builtin_amdgcn_mfma_f32_16x16x32_bf16(a3, bb, acc[3][nt], 0, 0, 0);
        if (more) b[nt] = *(const v8bf*)(bnxt + (size_t)nt * 512);
      }
      __builtin_amdgcn_s_setprio(0);
    }

    if (!last_dxy) STAGE_A(dxy + 1, (dxy + 1) & 1);
    __syncthreads();
  }
#undef STAGE_A

  size_t voxbase = ((size_t)x0 * 64 + (y0 + wcol)) * 64;
#pragma unroll
  for (int m = 0; m < 4; ++m)
#pragma unroll
    for (int nt = 0; nt < 9; ++nt) {
      int co = wc * 144 + nt * 16 + (lane & 15);
      float bias = qkvb[co];
#pragma unroll
      for (int r = 0; r < 4; ++r) {
        int vrow = m * 16 + (lane >> 4) * 4 + r;
        y[(voxbase + vrow) * 288 + co] = f2bf(acc[m][nt][r] + bias);
      }
    }
}

// ---------------- K4: Gram S[f,h,c,d] = sum_g q.k, plus norms ----------------
__global__ __launch_bounds__(256) void k_gram(const u16* __restrict__ y,
                                              float* __restrict__ S,
                                              float* __restrict__ qn2,
                                              float* __restrict__ kn2) {
  __shared__ u16 qk[8 * 192];
  int tid = threadIdx.x;
  int f = blockIdx.x >> 4, chunk = blockIdx.x & 15;
  int fx = f >> 4, fy = (f >> 2) & 3, fz = f & 3;
  int h = tid >> 6;
  int e0 = tid * 9;
  int ci[9], di[9];
#pragma unroll
  for (int i = 0; i < 9; ++i) {
    int rem = (e0 + i) % 576;
    ci[i] = rem / 24; di[i] = rem % 24;
  }
  float cacc[9];
#pragma unroll
  for (int i = 0; i < 9; ++i) cacc[i] = 0.f;
  float nacc = 0.f;

  for (int grp = 0; grp < 32; ++grp) {
    __syncthreads();
    for (int i = tid; i < 192; i += 256) {
      int rr = i / 24, c8 = i - rr * 24;
      int g = chunk * 256 + grp * 8 + rr;
      int gx = g >> 8, gy = (g >> 4) & 15, gz = g & 15;
      size_t vox = ((size_t)(gx * 4 + fx) * 64 + (gy * 4 + fy)) * 64 + (gz * 4 + fz);
      *(uint4*)&qk[rr * 192 + c8 * 8] = *(const uint4*)(y + vox * 288 + c8 * 8);
    }
    __syncthreads();
#pragma unroll 2
    for (int r = 0; r < 8; ++r) {
      const u16* row = &qk[r * 192];
#pragma unroll
      for (int i = 0; i < 9; ++i) {
        float qv = bf2f(row[h * 24 + ci[i]]);
        float kv = bf2f(row[96 + h * 24 + di[i]]);
        cacc[i] += qv * kv;
      }
      if (tid < 192) { float v = bf2f(row[tid]); nacc += v * v; }
    }
  }
  float* Sf = S + (size_t)f * 2304;
#pragma unroll
  for (int i = 0; i < 9; ++i) atomicAdd(&Sf[e0 + i], cacc[i]);
  if (tid < 96) atomicAdd(&qn2[f * 96 + tid], nacc);
  else if (tid < 192) atomicAdd(&kn2[f * 96 + tid - 96], nacc);
}

// ---------------- K5: normalize + softmax + fold out_w -> Mt[f][j][c'] (bf16) ----------------
__global__ __launch_bounds__(256) void k_attn(const float* __restrict__ S,
                                              const float* __restrict__ qn2,
                                              const float* __restrict__ kn2,
                                              const float* __restrict__ out_w,
                                              const float* __restrict__ temp,
                                              u16* __restrict__ Mt) {
  __shared__ float attn[2304];
  __shared__ float invq[96], invk[96];
  __shared__ float ow[9216];
  int tid = threadIdx.x;
  int f = blockIdx.x;
  if (tid < 96) {
    invq[tid] = 1.f / fmaxf(sqrtf(qn2[f * 96 + tid]), 1e-12f);
    invk[tid] = 1.f / fmaxf(sqrtf(kn2[f * 96 + tid]), 1e-12f);
  }
  for (int i = tid; i < 9216; i += 256) ow[i] = out_w[i];
  __syncthreads();
  if (tid < 96) {
    int h = tid / 24, c = tid % 24;
    float tmp = temp[h];
    const float* Sr = S + (size_t)f * 2304 + (size_t)h * 576 + c * 24;
    float lg[24];
    float mx = -1e30f;
#pragma unroll
    for (int d = 0; d < 24; ++d) {
      lg[d] = Sr[d] * invq[tid] * invk[h * 24 + d] * tmp;
      mx = fmaxf(mx, lg[d]);
    }
    float sum = 0.f;
#pragma unroll
    for (int d = 0; d < 24; ++d) { lg[d] = __expf(lg[d] - mx); sum += lg[d]; }
    float inv = 1.f / sum;
#pragma unroll
    for (int d = 0; d < 24; ++d) attn[h * 576 + c * 24 + d] = lg[d] * inv;
  }
  __syncthreads();
  for (int o = tid; o < 9216; o += 256) {
    int j = o / 96, cp = o - j * 96;
    int h2 = j / 24, d = j % 24;
    float s = 0.f;
#pragma unroll
    for (int cc = 0; cc < 24; ++cc)
      s += attn[h2 * 576 + cc * 24 + d] * ow[cp * 96 + h2 * 24 + cc];
    Mt[(size_t)f * 9216 + o] = f2bf(s);
  }
}

// ---------------- K6: out = Mt[f] @ v + out_b + x (residual), fp32 out ----------------
__global__ __launch_bounds__(256, 1) void k_final(const u16* __restrict__ y,
                                                  const u16* __restrict__ Mt,
                                                  const float* __restrict__ xin,
                                                  const float* __restrict__ out_b,
                                                  float* __restrict__ out) {
  __shared__ u16 mt4[4 * 9216];  // 73728 B: Mt for fz=0..3
  __shared__ u16 vst[64 * 96];   // 12288 B: one column's v
  int tid = threadIdx.x;
  int b = blockIdx.x;
  int fxy = b >> 4, chunk = b & 15;
  int fx = fxy >> 2, fy = fxy & 3;
  int x = fx + 4 * chunk;
  const uint4* msrc = (const uint4*)(Mt + (size_t)(fx * 16 + fy * 4) * 9216);
  for (int i = tid; i < 4608; i += 256) ((uint4*)mt4)[i] = msrc[i];
  int vox = tid >> 2, qo = tid & 3, fz = vox & 3;
  float ob[24];
#pragma unroll
  for (int cc = 0; cc < 24; ++cc) ob[cc] = out_b[qo * 24 + cc];

  for (int m = 0; m < 16; ++m) {
    int yy = fy + 4 * m;
    size_t colvox = ((size_t)x * 64 + yy) * 64;
    __syncthreads();
    for (int i = tid; i < 768; i += 256) {
      int vv = i / 12, c8 = i - vv * 12;
      ((uint4*)vst)[vv * 12 + c8] =
          *(const uint4*)(y + (colvox + vv) * 288 + 192 + c8 * 8);
    }
    __syncthreads();
    float acc[24];
#pragma unroll
    for (int cc = 0; cc < 24; ++cc) acc[cc] = ob[cc];
    const u16* mslice = &mt4[fz * 9216 + qo * 24];
#pragma unroll 4
    for (int j = 0; j < 96; ++j) {
      float vj = bf2f(vst[vox * 96 + j]);
      const uint4* mq = (const uint4*)(mslice + j * 96);
      uint4 m0 = mq[0], m1 = mq[1], m2 = mq[2];
      uint32_t mw[12];
      *(uint4*)&mw[0] = m0; *(uint4*)&mw[4] = m1; *(uint4*)&mw[8] = m2;
#pragma unroll
      for (int i2 = 0; i2 < 12; ++i2) {
        union { uint32_t u; float f; } lo, hi;
        lo.u = mw[i2] << 16; hi.u = mw[i2] & 0xFFFF0000u;
        acc[2 * i2] += vj * lo.f;
        acc[2 * i2 + 1] += vj * hi.f;
      }
    }
    const float4* xs = (const float4*)(xin + (colvox + vox) * 96 + qo * 24);
    float4* op = (float4*)(out + (colvox + vox) * 96 + qo * 24);
#pragma unroll
    for (int i2 = 0; i2 < 6; ++i2) {
      float4 xv = xs[i2];
      float4 r;
      r.x = acc[4 * i2 + 0] + xv.x;
      r.y = acc[4 * i2 + 1] + xv.y;
      r.z = acc[4 * i2 + 2] + xv.z;
      r.w = acc[4 * i2 + 3] + xv.w;
      op[i2] = r;
    }
  }
}

extern "C" void kernel_launch(void* const* d_in, const int* in_sizes, int n_in,
                              void* d_out, int out_size, void* d_ws, size_t ws_size,
                              hipStream_t stream) {
  const float* x  = (const float*)d_in[0];
  const float* g  = (const float*)d_in[1];
  const float* be = (const float*)d_in[2];
  const float* qw = (const float*)d_in[3];
  const float* qb = (const float*)d_in[4];
  const float* ow = (const float*)d_in[5];
  const float* ob = (const float*)d_in[6];
  const float* tp = (const float*)d_in[7];
  float* out = (float*)d_out;

  // xn (bf16, 50.3 MB) lives in d_out scratch space; dead before k_final
  // overwrites d_out with the final fp32 result.
  u16* xn = (u16*)d_out;

  char* w = (char*)d_ws;
  u16* y    = (u16*)(w);                          // 150,994,944 B
  u16* Wb   = (u16*)(w + 150994944);              // 1,492,992 B
  float* S  = (float*)(w + 152487936);            // 589,824 B
  float* qn2 = (float*)(w + 153077760);           // 24,576 B
  float* kn2 = (float*)(w + 153102336);           // 24,576 B
  u16* Mt   = (u16*)(w + 153126912);              // 1,179,648 B (end ~154.3 MB)

  hipLaunchKernelGGL(k_ln, dim3(4096), dim3(256), 0, stream, x, g, be, xn);
  hipLaunchKernelGGL(k_repack, dim3((27 * 3 * 18 * 64 + 255) / 256), dim3(256), 0, stream, qw, Wb);
  hipLaunchKernelGGL(k_zero, dim3(624), dim3(256), 0, stream, S, 159744);
  hipLaunchKernelGGL(k_conv, dim3(2048), dim3(256), 0, stream, xn, Wb, qb, y);
  hipLaunchKernelGGL(k_gram, dim3(1024), dim3(256), 0, stream, y, S, qn2, kn2);
  hipLaunchKernelGGL(k_attn, dim3(64), dim3(256), 0, stream, S, qn2, kn2, ow, tp, Mt);
  hipLaunchKernelGGL(k_final, dim3(256), dim3(256), 0, stream, y, Mt, x, ob, out);
}

// Round 6
// 698.908 us; speedup vs baseline: 1.2125x; 1.0840x over previous
//
#include <hip/hip_runtime.h>
#include <stdint.h>

typedef unsigned short u16;
typedef float f32x4 __attribute__((ext_vector_type(4)));
typedef float f32x16 __attribute__((ext_vector_type(16)));
typedef __bf16 v8bf __attribute__((ext_vector_type(8)));

static __device__ __forceinline__ float bf2f(u16 u) {
  union { uint32_t i; float f; } v; v.i = ((uint32_t)u) << 16; return v.f;
}
static __device__ __forceinline__ u16 f2bf(float f) {
  union { float f; uint32_t i; } v; v.f = f;
  uint32_t b = v.i;
  return (u16)((b + 0x7FFFu + ((b >> 16) & 1u)) >> 16);
}

// ---------------- K1: LayerNorm over C=96 (fp32 in) -> bf16 xn ----------------
__global__ __launch_bounds__(256) void k_ln(const float* __restrict__ x,
                                            const float* __restrict__ gamma,
                                            const float* __restrict__ beta,
                                            u16* __restrict__ xn) {
  int tid = threadIdx.x;
  int vox = blockIdx.x * 64 + (tid >> 2);
  int q = tid & 3;
  const float4* px = (const float4*)(x + (size_t)vox * 96 + q * 24);
  float f[24];
  *(float4*)&f[0]  = px[0]; *(float4*)&f[4]  = px[1]; *(float4*)&f[8]  = px[2];
  *(float4*)&f[12] = px[3]; *(float4*)&f[16] = px[4]; *(float4*)&f[20] = px[5];
  float s = 0.f, s2 = 0.f;
#pragma unroll
  for (int i = 0; i < 24; ++i) { s += f[i]; s2 += f[i] * f[i]; }
  s += __shfl_xor(s, 1);  s += __shfl_xor(s, 2);
  s2 += __shfl_xor(s2, 1); s2 += __shfl_xor(s2, 2);
  float mu = s * (1.f / 96.f);
  float var = s2 * (1.f / 96.f) - mu * mu;
  float rs = rsqrtf(var + 1e-5f);
  uint32_t ow[12];
#pragma unroll
  for (int i = 0; i < 12; ++i) {
    int c0 = q * 24 + 2 * i;
    float v0 = (f[2 * i]     - mu) * rs * gamma[c0]     + beta[c0];
    float v1 = (f[2 * i + 1] - mu) * rs * gamma[c0 + 1] + beta[c0 + 1];
    ow[i] = (uint32_t)f2bf(v0) | ((uint32_t)f2bf(v1) << 16);
  }
  uint4* po = (uint4*)(xn + (size_t)vox * 96 + q * 24);
  po[0] = *(uint4*)&ow[0]; po[1] = *(uint4*)&ow[4]; po[2] = *(uint4*)&ow[8];
}

// ---------------- K2: repack qkv_w (fp32) into bf16 MFMA B-fragment layout ----------------
// Wb[tap][ks][nt][lane][j] : value = W[tap][ci=ks*32+(lane>>4)*8+j][co=nt*16+(lane&15)]
__global__ __launch_bounds__(256) void k_repack(const float* __restrict__ qw,
                                                u16* __restrict__ Wb) {
  int t = blockIdx.x * 256 + threadIdx.x;
  if (t >= 27 * 3 * 18 * 64) return;
  int l = t & 63;
  int rest = t >> 6;
  int nt = rest % 18;
  int ks = (rest / 18) % 3;
  int tap = rest / 54;
  int co = nt * 16 + (l & 15);
  int cibase = ks * 32 + (l >> 4) * 8;
  u16 vals[8];
#pragma unroll
  for (int j = 0; j < 8; ++j)
    vals[j] = f2bf(qw[((size_t)tap * 96 + cibase + j) * 288 + co]);
  *(uint4*)(Wb + (size_t)t * 8) = *(uint4*)vals;
}

// ---------------- K3: conv3d 3x3x3 96->288 via MFMA bf16 ----------------
// Block = TWO adjacent z-columns (128 rows), 4 waves; wave = 1 column x 144 cols.
// A: double-buffered LDS with T14 async split: STAGE_LOAD (global->regs) issued
// BEFORE the t-loop (~1600 cyc of MFMA hides latency), STAGE_WRITE (regs->LDS)
// after. B: register-rotated 1-deep pipeline across (tap,ks) steps.
__global__ __launch_bounds__(256, 2) void k_conv(const u16* __restrict__ xn,
                                                 const u16* __restrict__ Wb,
                                                 const float* __restrict__ qkvb,
                                                 u16* __restrict__ y) {
  __shared__ u16 As[2][2 * 66 * 104];  // 54,912 B; pitch 104 (2-way benign)
  int tid = threadIdx.x;
  // bijective XCD swizzle: 2048 blocks, 8 XCDs, 256 blocks/XCD.
  int bid = blockIdx.x;
  int swz = (bid & 7) * 256 + (bid >> 3);
  int x0 = swz >> 5;
  int y0 = (swz & 31) * 2;
  int lane = tid & 63, w = tid >> 6;
  int wcol = w >> 1, wc = w & 1;

  f32x4 acc[4][9];
#pragma unroll
  for (int m = 0; m < 4; ++m)
#pragma unroll
    for (int n = 0; n < 9; ++n) acc[m][n] = (f32x4)0.f;

  const u16* wbase = Wb + (size_t)(wc * 9) * 512 + (size_t)lane * 8;

  uint4 sreg[7];  // 1584 items / 256 threads -> up to 7 per thread
  auto stage_load = [&](int dxy_) {
    int dx_ = dxy_ / 3, dy_ = dxy_ % 3;
    int xx_ = x0 + dx_ - 1;
#pragma unroll
    for (int it = 0; it < 7; ++it) {
      int i = tid + it * 256;
      uint4 v_ = make_uint4(0u, 0u, 0u, 0u);
      if (i < 1584) {
        int c_ = i / 792, rem_ = i - c_ * 792;
        int row_ = rem_ / 12, c8_ = rem_ - row_ * 12;
        int yy_ = y0 + c_ + dy_ - 1;
        if (((unsigned)xx_ < 64u) && ((unsigned)yy_ < 64u) && row_ >= 1 && row_ <= 64)
          v_ = ((const uint4*)(xn + ((size_t)(xx_ * 64 + yy_) * 64) * 96))[(row_ - 1) * 12 + c8_];
      }
      sreg[it] = v_;
    }
  };
  auto stage_write = [&](int bufi) {
#pragma unroll
    for (int it = 0; it < 7; ++it) {
      int i = tid + it * 256;
      if (i < 1584) {
        int c_ = i / 792, rem_ = i - c_ * 792;
        int row_ = rem_ / 12, c8_ = rem_ - row_ * 12;
        *(uint4*)&As[bufi][(c_ * 66 + row_) * 104 + c8_ * 8] = sreg[it];
      }
    }
  };

  stage_load(0);
  stage_write(0);
  __syncthreads();

  // preload B for (dxy=0, t=0)
  v8bf b[9];
#pragma unroll
  for (int nt = 0; nt < 9; ++nt)
    b[nt] = *(const v8bf*)(wbase + (size_t)nt * 512);

  for (int dxy = 0; dxy < 9; ++dxy) {
    const u16* Ab = &As[dxy & 1][0];
    const u16* base2 = wbase + (size_t)dxy * 9 * 9216;
    bool last_dxy = (dxy == 8);

    if (!last_dxy) stage_load(dxy + 1);  // issue global loads early (T14)

#pragma unroll
    for (int t = 0; t < 9; ++t) {
      int dz = t / 3, ks = t - dz * 3;
      int ar = (lane & 15) + dz;
      int ac = ks * 32 + (lane >> 4) * 8;
      const u16* abase = &Ab[(wcol * 66 + ar) * 104 + ac];
      v8bf a0 = *(const v8bf*)(abase);
      v8bf a1 = *(const v8bf*)(abase + 16 * 104);
      v8bf a2 = *(const v8bf*)(abase + 32 * 104);
      v8bf a3 = *(const v8bf*)(abase + 48 * 104);
      const u16* bnxt = base2 + (size_t)(t + 1) * 9216;
      bool more = (t < 8) || !last_dxy;
      __builtin_amdgcn_s_setprio(1);
#pragma unroll
      for (int nt = 0; nt < 9; ++nt) {
        v8bf bb = b[nt];
        acc[0][nt] = __builtin_amdgcn_mfma_f32_16x16x32_bf16(a0, bb, acc[0][nt], 0, 0, 0);
        acc[1][nt] = __builtin_amdgcn_mfma_f32_16x16x32_bf16(a1, bb, acc[1][nt], 0, 0, 0);
        acc[2][nt] = __builtin_amdgcn_mfma_f32_16x16x32_bf16(a2, bb, acc[2][nt], 0, 0, 0);
        acc[3][nt] = __builtin_amdgcn_mfma_f32_16x16x32_bf16(a3, bb, acc[3][nt], 0, 0, 0);
        if (more) b[nt] = *(const v8bf*)(bnxt + (size_t)nt * 512);
      }
      __builtin_amdgcn_s_setprio(0);
    }

    if (!last_dxy) stage_write((dxy + 1) & 1);
    __syncthreads();
  }

  size_t voxbase = ((size_t)x0 * 64 + (y0 + wcol)) * 64;
#pragma unroll
  for (int m = 0; m < 4; ++m)
#pragma unroll
    for (int nt = 0; nt < 9; ++nt) {
      int co = wc * 144 + nt * 16 + (lane & 15);
      float bias = qkvb[co];
#pragma unroll
      for (int r = 0; r < 4; ++r) {
        int vrow = m * 16 + (lane >> 4) * 4 + r;
        y[(voxbase + vrow) * 288 + co] = f2bf(acc[m][nt][r] + bias);
      }
    }
}

// ---------------- K4: Gram via MFMA 32x32x16 ----------------
// S[f,h,c,d] = sum_g q.k ; qn2/kn2 = diagonals of QQ/KK Grams (free: for
// 32x32x16, A-frag(row=l&31,k=(l>>5)*8+j) and B-frag(col=l&31,k=...) have
// IDENTICAL register layouts when indexing (channel, g) -> QQ=mfma(aq,aq).
// Block = (f, chunk of 256 g); 4 waves = 4 heads; per 16 g: 16 ds_read_u16
// + 3 MFMA. LDS [16 g][292 u16] (584 B pitch: 8g-offset = 16 banks ->
// conflict-free fragment reads). Partials written per chunk (no atomics).
__global__ __launch_bounds__(256) void k_gram2(const u16* __restrict__ y,
                                               float* __restrict__ S_part,
                                               float* __restrict__ qn_part,
                                               float* __restrict__ kn_part) {
  __shared__ u16 buf[2][16 * 292];
  int tid = threadIdx.x;
  int f = blockIdx.x >> 4, chunk = blockIdx.x & 15;
  int fx = f >> 4, fy = (f >> 2) & 3, fz = f & 3;
  int l = tid & 63, h = tid >> 6;

  f32x16 aqk = (f32x16)0.f, aqq = (f32x16)0.f, akk = (f32x16)0.f;

  // staging: items i in [0,384): g_loc=i/24, c8=i%24 (8 channels each).
  // channel run c0=c8*8 stays within one head's 24-block (24=3*8), so the
  // 8 u16 land contiguously at dst = [kflag*128 + h'*32 + c'].
  int i0 = tid;
  int gl0 = i0 / 24, c80 = i0 - gl0 * 24;
  int c00 = c80 * 8;
  int dst0 = (c00 < 96) ? ((c00 / 24) * 32 + (c00 % 24))
                        : (128 + ((c00 - 96) / 24) * 32 + ((c00 - 96) % 24));
  int i1 = tid + 256;
  int gl1 = i1 / 24, c81 = i1 - gl1 * 24;
  int c01 = c81 * 8;
  int dst1 = (c01 < 96) ? ((c01 / 24) * 32 + (c01 % 24))
                        : (128 + ((c01 - 96) / 24) * 32 + ((c01 - 96) % 24));
  bool has1 = (tid < 128);

  uint4 s0, s1;
  auto gload = [&](int sub) {
    int gbase = chunk * 256 + sub * 16;
    {
      int g = gbase + gl0;
      int gx = g >> 8, gy = (g >> 4) & 15, gz = g & 15;
      size_t vox = ((size_t)(gx * 4 + fx) * 64 + (gy * 4 + fy)) * 64 + (gz * 4 + fz);
      s0 = *(const uint4*)(y + vox * 288 + c00);
    }
    if (has1) {
      int g = gbase + gl1;
      int gx = g >> 8, gy = (g >> 4) & 15, gz = g & 15;
      size_t vox = ((size_t)(gx * 4 + fx) * 64 + (gy * 4 + fy)) * 64 + (gz * 4 + fz);
      s1 = *(const uint4*)(y + vox * 288 + c01);
    }
  };
  auto gwrite = [&](int bufi) {
    u16* p0 = &buf[bufi][gl0 * 292 + dst0];
    *(uint2*)p0 = make_uint2(s0.x, s0.y);
    *(uint2*)(p0 + 4) = make_uint2(s0.z, s0.w);
    if (has1) {
      u16* p1 = &buf[bufi][gl1 * 292 + dst1];
      *(uint2*)p1 = make_uint2(s1.x, s1.y);
      *(uint2*)(p1 + 4) = make_uint2(s1.z, s1.w);
    }
  };

  gload(0);
  gwrite(0);
  __syncthreads();

  for (int sub = 0; sub < 16; ++sub) {
    if (sub < 15) gload(sub + 1);  // issue next-tile loads early
    const u16* bb = &buf[sub & 1][(l >> 5) * 8 * 292 + h * 32 + (l & 31)];
    v8bf aq, ak;
#pragma unroll
    for (int j = 0; j < 8; ++j) {
      ((u16*)&aq)[j] = bb[j * 292];
      ((u16*)&ak)[j] = bb[j * 292 + 128];
    }
    aqk = __builtin_amdgcn_mfma_f32_32x32x16_bf16(aq, ak, aqk, 0, 0, 0);
    aqq = __builtin_amdgcn_mfma_f32_32x32x16_bf16(aq, aq, aqq, 0, 0, 0);
    akk = __builtin_amdgcn_mfma_f32_32x32x16_bf16(ak, ak, akk, 0, 0, 0);
    if (sub < 15) gwrite((sub + 1) & 1);
    __syncthreads();
  }

  // writeout: D layout 32x32: col=l&31, row=(reg&3)+8*(reg>>2)+4*(l>>5);
  // regs 12..15 -> rows>=24 (discard). Diag (c,c) lives at reg dreg below.
  int col = l & 31, hi = l >> 5;
  if (col < 24) {
    float* Sp = S_part + (((size_t)(chunk * 64 + f)) * 4 + h) * 576;
#pragma unroll
    for (int reg = 0; reg < 12; ++reg) {
      int row = (reg & 3) + 8 * (reg >> 2) + 4 * hi;
      Sp[row * 24 + col] = aqk[reg];
    }
    int sel = (col & 7) - 4 * hi;
    if (sel >= 0 && sel < 4) {
      int dreg = (col >> 3) * 4 + sel;
      float qn = 0.f, kn = 0.f;
#pragma unroll
      for (int r = 0; r < 12; ++r)
        if (r == dreg) { qn = aqq[r]; kn = akk[r]; }
      qn_part[((size_t)(chunk * 64 + f)) * 96 + h * 24 + col] = qn;
      kn_part[((size_t)(chunk * 64 + f)) * 96 + h * 24 + col] = kn;
    }
  }
}

// ---------------- K5: sum partials + normalize + softmax + fold out_w -> Mt ----------------
__global__ __launch_bounds__(256) void k_attn(const float* __restrict__ S_part,
                                              const float* __restrict__ qn_part,
                                              const float* __restrict__ kn_part,
                                              const float* __restrict__ out_w,
                                              const float* __restrict__ temp,
                                              u16* __restrict__ Mt) {
  __shared__ float Ssum[2304];
  __shared__ float attn[2304];
  __shared__ float invq[96], invk[96];
  __shared__ float ow[9216];
  int tid = threadIdx.x;
  int f = blockIdx.x;
  for (int o = tid; o < 2304; o += 256) {
    float s = 0.f;
#pragma unroll
    for (int c = 0; c < 16; ++c) s += S_part[((size_t)(c * 64 + f)) * 2304 + o];
    Ssum[o] = s;
  }
  if (tid < 96) {
    float qn = 0.f, kn = 0.f;
#pragma unroll
    for (int c = 0; c < 16; ++c) {
      qn += qn_part[((size_t)(c * 64 + f)) * 96 + tid];
      kn += kn_part[((size_t)(c * 64 + f)) * 96 + tid];
    }
    invq[tid] = 1.f / fmaxf(sqrtf(qn), 1e-12f);
    invk[tid] = 1.f / fmaxf(sqrtf(kn), 1e-12f);
  }
  for (int i = tid; i < 9216; i += 256) ow[i] = out_w[i];
  __syncthreads();
  if (tid < 96) {
    int h = tid / 24, c = tid % 24;
    float tmp = temp[h];
    const float* Sr = &Ssum[h * 576 + c * 24];
    float lg[24];
    float mx = -1e30f;
#pragma unroll
    for (int d = 0; d < 24; ++d) {
      lg[d] = Sr[d] * invq[tid] * invk[h * 24 + d] * tmp;
      mx = fmaxf(mx, lg[d]);
    }
    float sum = 0.f;
#pragma unroll
    for (int d = 0; d < 24; ++d) { lg[d] = __expf(lg[d] - mx); sum += lg[d]; }
    float inv = 1.f / sum;
#pragma unroll
    for (int d = 0; d < 24; ++d) attn[h * 576 + c * 24 + d] = lg[d] * inv;
  }
  __syncthreads();
  for (int o = tid; o < 9216; o += 256) {
    int j = o / 96, cp = o - j * 96;
    int h2 = j / 24, d = j % 24;
    float s = 0.f;
#pragma unroll
    for (int cc = 0; cc < 24; ++cc)
      s += attn[h2 * 576 + cc * 24 + d] * ow[cp * 96 + h2 * 24 + cc];
    Mt[(size_t)f * 9216 + o] = f2bf(s);
  }
}

// ---------------- K6: out = Mt[f] @ v + out_b + x (residual), fp32 out ----------------
__global__ __launch_bounds__(256, 1) void k_final(const u16* __restrict__ y,
                                                  const u16* __restrict__ Mt,
                                                  const float* __restrict__ xin,
                                                  const float* __restrict__ out_b,
                                                  float* __restrict__ out) {
  __shared__ u16 mt4[4 * 9216];  // 73728 B: Mt for fz=0..3
  __shared__ u16 vst[64 * 96];   // 12288 B: one column's v
  int tid = threadIdx.x;
  int b = blockIdx.x;
  int fxy = b >> 4, chunk = b & 15;
  int fx = fxy >> 2, fy = fxy & 3;
  int x = fx + 4 * chunk;
  const uint4* msrc = (const uint4*)(Mt + (size_t)(fx * 16 + fy * 4) * 9216);
  for (int i = tid; i < 4608; i += 256) ((uint4*)mt4)[i] = msrc[i];
  int vox = tid >> 2, qo = tid & 3, fz = vox & 3;
  float ob[24];
#pragma unroll
  for (int cc = 0; cc < 24; ++cc) ob[cc] = out_b[qo * 24 + cc];

  for (int m = 0; m < 16; ++m) {
    int yy = fy + 4 * m;
    size_t colvox = ((size_t)x * 64 + yy) * 64;
    __syncthreads();
    for (int i = tid; i < 768; i += 256) {
      int vv = i / 12, c8 = i - vv * 12;
      ((uint4*)vst)[vv * 12 + c8] =
          *(const uint4*)(y + (colvox + vv) * 288 + 192 + c8 * 8);
    }
    __syncthreads();
    float acc[24];
#pragma unroll
    for (int cc = 0; cc < 24; ++cc) acc[cc] = ob[cc];
    const u16* mslice = &mt4[fz * 9216 + qo * 24];
#pragma unroll 4
    for (int j = 0; j < 96; ++j) {
      float vj = bf2f(vst[vox * 96 + j]);
      const uint4* mq = (const uint4*)(mslice + j * 96);
      uint4 m0 = mq[0], m1 = mq[1], m2 = mq[2];
      uint32_t mw[12];
      *(uint4*)&mw[0] = m0; *(uint4*)&mw[4] = m1; *(uint4*)&mw[8] = m2;
#pragma unroll
      for (int i2 = 0; i2 < 12; ++i2) {
        union { uint32_t u; float f; } lo, hi;
        lo.u = mw[i2] << 16; hi.u = mw[i2] & 0xFFFF0000u;
        acc[2 * i2] += vj * lo.f;
        acc[2 * i2 + 1] += vj * hi.f;
      }
    }
    const float4* xs = (const float4*)(xin + (colvox + vox) * 96 + qo * 24);
    float4* op = (float4*)(out + (colvox + vox) * 96 + qo * 24);
#pragma unroll
    for (int i2 = 0; i2 < 6; ++i2) {
      float4 xv = xs[i2];
      float4 r;
      r.x = acc[4 * i2 + 0] + xv.x;
      r.y = acc[4 * i2 + 1] + xv.y;
      r.z = acc[4 * i2 + 2] + xv.z;
      r.w = acc[4 * i2 + 3] + xv.w;
      op[i2] = r;
    }
  }
}

extern "C" void kernel_launch(void* const* d_in, const int* in_sizes, int n_in,
                              void* d_out, int out_size, void* d_ws, size_t ws_size,
                              hipStream_t stream) {
  const float* x  = (const float*)d_in[0];
  const float* g  = (const float*)d_in[1];
  const float* be = (const float*)d_in[2];
  const float* qw = (const float*)d_in[3];
  const float* qb = (const float*)d_in[4];
  const float* ow = (const float*)d_in[5];
  const float* ob = (const float*)d_in[6];
  const float* tp = (const float*)d_in[7];
  float* out = (float*)d_out;

  // d_out (100.7 MB) doubles as scratch until k_final overwrites it:
  //   xn (bf16, 50.3 MB) dead after k_conv; S/qn/kn partials dead after k_attn.
  u16* xn = (u16*)d_out;
  float* S_part  = (float*)((char*)d_out + 50331648);  // 9,437,184 B
  float* qn_part = (float*)((char*)d_out + 59768832);  //   393,216 B
  float* kn_part = (float*)((char*)d_out + 60162048);  //   393,216 B

  char* w = (char*)d_ws;
  u16* y  = (u16*)(w);                 // 150,994,944 B
  u16* Wb = (u16*)(w + 150994944);     //   1,492,992 B
  u16* Mt = (u16*)(w + 152487936);     //   1,179,648 B (end ~153.7 MB)

  hipLaunchKernelGGL(k_ln, dim3(4096), dim3(256), 0, stream, x, g, be, xn);
  hipLaunchKernelGGL(k_repack, dim3((27 * 3 * 18 * 64 + 255) / 256), dim3(256), 0, stream, qw, Wb);
  hipLaunchKernelGGL(k_conv, dim3(2048), dim3(256), 0, stream, xn, Wb, qb, y);
  hipLaunchKernelGGL(k_gram2, dim3(1024), dim3(256), 0, stream, y, S_part, qn_part, kn_part);
  hipLaunchKernelGGL(k_attn, dim3(64), dim3(256), 0, stream, S_part, qn_part, kn_part, ow, tp, Mt);
  hipLaunchKernelGGL(k_final, dim3(256), dim3(256), 0, stream, y, Mt, x, ob, out);
}